// Round 5
// baseline (5088.198 us; speedup 1.0000x reference)
//
#include <hip/hip_runtime.h>

#define BB 512
#define TT 2048
#define DD 8
#define HH 64
#define GG 256  // 4*H gates

typedef float f32x4 __attribute__((ext_vector_type(4)));
typedef float f32x2 __attribute__((ext_vector_type(2)));

__device__ __forceinline__ float sigm(float x) {
  return 1.0f / (1.0f + __expf(-x));
}
__device__ __forceinline__ float tanh_fast(float x) {
  // tanh(x) = 1 - 2/(exp(2x)+1); saturates correctly at +/-inf
  return 1.0f - 2.0f / (__expf(2.0f * x) + 1.0f);
}
// v_pk_fma_f32: one VOP3P inst = 2 fp32 FMAs. Halves the dot-product
// instruction stream vs scalar fmaf.
__device__ __forceinline__ f32x2 pkfma(f32x2 a, f32x2 b, f32x2 c) {
  return __builtin_elementwise_fma(a, b, c);
}
__device__ __forceinline__ f32x2 lo2(f32x4 v) { return __builtin_shufflevector(v, v, 0, 1); }
__device__ __forceinline__ f32x2 hi2(f32x4 v) { return __builtin_shufflevector(v, v, 2, 3); }

// Model revision (R4 evidence): KEEP3 asm pins ran clean and changed NOTHING
// (VGPR=108, WRITE_SIZE=16KB -> no scratch, dur identical). Weights were
// already register-file-resident (AGPR side of the unified file; VGPR_Count
// doesn't report AGPRs). If they streamed from L2 the floor would be
// ~6000 cyc/step > measured ~3600 -- contradiction. The kernel is
// VALU-ISSUE-BOUND on overhead: 128 v_readlane/thread-step (~40% of issue),
// likely accvgpr moves, and 4x-replicated c/h updates.
// This round attacks issue volume directly:
//  - h0/h1 broadcast via uniform ds_read_b128 (DS pipe) instead of readlane
//  - v_pk_fma_f32 halves the 192-FMA dot stream
//  - only wave 0 maintains c/h state (was replicated in all 4 waves)
// Cost: 3 barriers/step instead of 2.
__global__ void __launch_bounds__(256)
    __attribute__((amdgpu_waves_per_eu(1, 2)))
    lstm2_fused(
        const float* __restrict__ x,
        const float* __restrict__ w_ih0, const float* __restrict__ w_hh0,
        const float* __restrict__ b_ih0, const float* __restrict__ b_hh0,
        const float* __restrict__ w_ih1, const float* __restrict__ w_hh1,
        const float* __restrict__ b_ih1, const float* __restrict__ b_hh1,
        const float* __restrict__ w_out, const float* __restrict__ b_out,
        float* __restrict__ out)
{
  const int b    = blockIdx.x;
  const int tid  = threadIdx.x;   // gate index g
  const int lane = tid & 63;
  const int wave = tid >> 6;      // 0:i 1:f 2:g 3:o

  __shared__ __align__(16) float g0buf[2][GG];
  __shared__ __align__(16) float g1buf[2][GG];
  __shared__ __align__(16) float h0b[2][HH];  // h0[t]   broadcast quads
  __shared__ __align__(16) float h1b[2][HH];  // h1[t-1] broadcast quads

  // ---- one-time: this thread's weight rows into register tuples ----
  f32x4 wa4[16];  // w_ih1 row tid (consumes h0[t])
  f32x4 wb4[16];  // w_hh0 row tid (consumes h0[t] -> next-step layer0)
  f32x4 wc4[16];  // w_hh1 row tid (consumes h1[t-1])
  {
    const f32x4* pa = reinterpret_cast<const f32x4*>(w_ih1 + tid * HH);
    const f32x4* pb = reinterpret_cast<const f32x4*>(w_hh0 + tid * HH);
    const f32x4* pc = reinterpret_cast<const f32x4*>(w_hh1 + tid * HH);
#pragma unroll
    for (int q = 0; q < 16; ++q) { wa4[q] = pa[q]; wb4[q] = pb[q]; wc4[q] = pc[q]; }
  }
  float wih0[DD];
#pragma unroll
  for (int k = 0; k < DD; ++k) wih0[k] = w_ih0[tid * DD + k];
  const float bias0 = b_ih0[tid] + b_hh0[tid];
  const float bias1 = b_ih1[tid] + b_hh1[tid];

  // c/h state: maintained by wave 0 only (lane j holds element j)
  float h0 = 0.0f, c0 = 0.0f, h1 = 0.0f, c1 = 0.0f;
  // layer0 preactivation carried across steps: acc0 = bias0 + Whh0.h0[t-1]
  float acc0 = bias0;

  const f32x4* xq = reinterpret_cast<const f32x4*>(x + (size_t)b * TT * DD);
  f32x4 xa = xq[0], xb_ = xq[1];  // x[t=0] (wave-uniform)

  for (int t = 0; t < TT; ++t) {
    const int p = t & 1;

    // ---- A: finish layer0 preactivation with x[t], activate gate ----
    acc0 = fmaf(wih0[0], xa.x, acc0);
    acc0 = fmaf(wih0[1], xa.y, acc0);
    acc0 = fmaf(wih0[2], xa.z, acc0);
    acc0 = fmaf(wih0[3], xa.w, acc0);
    acc0 = fmaf(wih0[4], xb_.x, acc0);
    acc0 = fmaf(wih0[5], xb_.y, acc0);
    acc0 = fmaf(wih0[6], xb_.z, acc0);
    acc0 = fmaf(wih0[7], xb_.w, acc0);
    {
      const int tn = (t + 1 < TT) ? (t + 1) : (TT - 1);
      xa  = xq[2 * tn];
      xb_ = xq[2 * tn + 1];
    }
    const float a0 = (wave == 2) ? tanh_fast(acc0) : sigm(acc0);
    g0buf[p][tid] = a0;
    if (wave == 0) h1b[p][lane] = h1;  // h1[t-1] (0 at t=0)
    __syncthreads();  // #1: g0buf + h1b visible

    // ---- B: wave 0 updates c0/h0, publishes h0[t] ----
    if (wave == 0) {
      const float gi = g0buf[p][lane];
      const float gf = g0buf[p][HH + lane];
      const float gg = g0buf[p][2 * HH + lane];
      const float go = g0buf[p][3 * HH + lane];
      c0 = fmaf(gf, c0, gi * gg);
      h0 = go * tanh_fast(c0);
      h0b[p][lane] = h0;
    }
    __syncthreads();  // #2: h0b visible

    // ---- C: three dot products via uniform LDS quad broadcasts ----
    f32x2 s1 = {0.0f, 0.0f};  // wa . h0[t]
    f32x2 s0 = {0.0f, 0.0f};  // wb . h0[t]   (next-step layer0)
    f32x2 sc = {0.0f, 0.0f};  // wc . h1[t-1]
    const f32x4* hq4 = reinterpret_cast<const f32x4*>(h0b[p]);
    const f32x4* gq4 = reinterpret_cast<const f32x4*>(h1b[p]);
#pragma unroll
    for (int q = 0; q < 16; ++q) {
      const f32x4 hq = hq4[q];  // uniform address -> broadcast, no conflict
      const f32x4 gq = gq4[q];
      s1 = pkfma(lo2(wa4[q]), lo2(hq), s1);
      s0 = pkfma(lo2(wb4[q]), lo2(hq), s0);
      sc = pkfma(lo2(wc4[q]), lo2(gq), sc);
      s1 = pkfma(hi2(wa4[q]), hi2(hq), s1);
      s0 = pkfma(hi2(wb4[q]), hi2(hq), s0);
      sc = pkfma(hi2(wc4[q]), hi2(gq), sc);
    }
    const float accg1 = bias1 + s1.x + s1.y + sc.x + sc.y;
    const float a1 = (wave == 2) ? tanh_fast(accg1) : sigm(accg1);
    g1buf[p][tid] = a1;
    __syncthreads();  // #3: g1buf visible

    // ---- D: wave 0 updates c1/h1 ----
    if (wave == 0) {
      const float gi = g1buf[p][lane];
      const float gf = g1buf[p][HH + lane];
      const float gg = g1buf[p][2 * HH + lane];
      const float go = g1buf[p][3 * HH + lane];
      c1 = fmaf(gf, c1, gi * gg);
      h1 = go * tanh_fast(c1);
    }
    acc0 = bias0 + s0.x + s0.y;  // carry Whh0.h0[t] into step t+1
  }

  // ---- head: out[b] = dot(h1, w_out) + b_out (wave 0 holds h1) ----
  if (wave == 0) {
    float v = h1 * w_out[lane];
#pragma unroll
    for (int off = 32; off; off >>= 1) v += __shfl_down(v, off);
    if (lane == 0) out[b] = v + b_out[0];
  }
}

extern "C" void kernel_launch(void* const* d_in, const int* in_sizes, int n_in,
                              void* d_out, int out_size, void* d_ws, size_t ws_size,
                              hipStream_t stream) {
  const float* x     = (const float*)d_in[0];
  const float* w_ih0 = (const float*)d_in[1];
  const float* w_hh0 = (const float*)d_in[2];
  const float* b_ih0 = (const float*)d_in[3];
  const float* b_hh0 = (const float*)d_in[4];
  const float* w_ih1 = (const float*)d_in[5];
  const float* w_hh1 = (const float*)d_in[6];
  const float* b_ih1 = (const float*)d_in[7];
  const float* b_hh1 = (const float*)d_in[8];
  const float* w_out = (const float*)d_in[9];
  const float* b_out = (const float*)d_in[10];
  float* out = (float*)d_out;

  lstm2_fused<<<dim3(BB), dim3(256), 0, stream>>>(
      x, w_ih0, w_hh0, b_ih0, b_hh0,
      w_ih1, w_hh1, b_ih1, b_hh1,
      w_out, b_out, out);
}

// Round 6
// 3376.030 us; speedup vs baseline: 1.5072x; 1.5072x over previous
//
#include <hip/hip_runtime.h>

#define BB 512
#define TT 2048
#define DD 8
#define HH 64
#define NB 16              // batch columns per block (one MFMA N-tile)
#define NBLK (BB / NB)     // 32 blocks

typedef _Float16 f16x8 __attribute__((ext_vector_type(8)));
typedef float    f32x4 __attribute__((ext_vector_type(4)));

__device__ __forceinline__ float sigm(float x) { return 1.0f / (1.0f + __expf(-x)); }
__device__ __forceinline__ float tanh_fast(float x) {
  // tanh(x) = 1 - 2/(exp(2x)+1); saturates correctly at +/-inf
  return 1.0f - 2.0f / (__expf(2.0f * x) + 1.0f);
}
__device__ __forceinline__ f16x8 cvt8(const float* __restrict__ p) {
  f16x8 r;
#pragma unroll
  for (int e = 0; e < 8; ++e) r[e] = (_Float16)p[e];
  return r;
}

// MFMA 16x16x32 f16 layouts (gfx950):
//   A: row = lane&15, k = 8*(lane>>4)+e   (e = 0..7)
//   B: col = lane&15, k = 8*(lane>>4)+e
//   C/D: col = lane&15, row = 4*(lane>>4)+r  (r = 0..3)  [guide §3, m89-verified]
//
// Wave q owns M-tiles {q, q+4, q+8, q+12} = one tile of each gate type
// (i,f,g,o) covering hidden k in [16q, 16q+16). Hence the c/h update is
// wave-local in C-layout: lane holds i,f,g,o for 4 (k, n) pairs.
//
// h is republished per step as fp16 into LDS [n][64k], 16B-block XOR
// swizzle (blk ^= n&7) -> ds_write_b16 (2-way) and one conflict-free
// ds_read_b128 per B-fragment. Double-buffered by t-parity (WAR safety
// across the 2 barriers/step).
__global__ void __launch_bounds__(256, 1)
lstm2_mfma(const float* __restrict__ x,
           const float* __restrict__ w_ih0, const float* __restrict__ w_hh0,
           const float* __restrict__ b_ih0, const float* __restrict__ b_hh0,
           const float* __restrict__ w_ih1, const float* __restrict__ w_hh1,
           const float* __restrict__ b_ih1, const float* __restrict__ b_hh1,
           const float* __restrict__ w_out, const float* __restrict__ b_out,
           float* __restrict__ out)
{
  const int tid  = threadIdx.x;
  const int lane = tid & 63;
  const int q    = tid >> 6;    // wave 0..3
  const int lg   = lane >> 4;   // k-group 0..3
  const int ar   = lane & 15;   // A-row / B-col / batch n

  __shared__ __align__(16) unsigned char h0buf[2][NB][128];  // fp16 h0, parity-dbuf
  __shared__ __align__(16) unsigned char h1buf[2][NB][128];  // fp16 h1
  __shared__ float hout[HH][NB];

  // zero both parity buffers (h1buf[1] is read at t=0)
  {
    float* z0 = (float*)h0buf;
    float* z1 = (float*)h1buf;
    for (int i = tid; i < (int)(sizeof(h0buf) / 4); i += 256) { z0[i] = 0.f; z1[i] = 0.f; }
  }

  // ---- static A-fragments (fp16-packed, ~112 VGPRs) + biases ----
  f16x8 a_x[4], a_h0[4][2], a_i1[4][2], a_h1[4][2];
  float b0v[4][4], b1v[4][4];
#pragma unroll
  for (int ti = 0; ti < 4; ++ti) {
    const int tile = q + 4 * ti;        // ti: 0=i 1=f 2=g 3=o
    const int ga   = 16 * tile + ar;    // A-row gate index
    f16x8 zf = {};
    a_x[ti] = zf;
    if (lg == 0) a_x[ti] = cvt8(w_ih0 + ga * DD);   // k=0..7 live, rest 0
#pragma unroll
    for (int kf = 0; kf < 2; ++kf) {
      const int off = ga * HH + kf * 32 + lg * 8;
      a_h0[ti][kf] = cvt8(w_hh0 + off);
      a_i1[ti][kf] = cvt8(w_ih1 + off);
      a_h1[ti][kf] = cvt8(w_hh1 + off);
    }
#pragma unroll
    for (int r = 0; r < 4; ++r) {
      const int gc = 16 * tile + 4 * lg + r;        // C-row gate index
      b0v[ti][r] = b_ih0[gc] + b_hh0[gc];
      b1v[ti][r] = b_ih1[gc] + b_hh1[gc];
    }
  }

  // x stream: every lane tracks batch row `ar` (4-wave duplication -> L1 hits)
  const float4* xrow =
      (const float4*)(x + (size_t)(blockIdx.x * NB + ar) * TT * DD);
  float4 xA = xrow[0], xB = xrow[1];

  f16x8 hf0_0 = {}, hf0_1 = {}, hf1_0 = {}, hf1_1 = {};  // B-frags (h0[t-1], h1[t-1])
  float c0v[4] = {0.f, 0.f, 0.f, 0.f};
  float c1v[4] = {0.f, 0.f, 0.f, 0.f};
  float hv1[4] = {0.f, 0.f, 0.f, 0.f};

  __syncthreads();

  for (int t = 0; t < TT; ++t) {
    const int p = t & 1;

    // ---- build x B-frag (k=0..7 live in lane-group 0; A is 0 for k>=8) ----
    f16x8 xf = {};
    if (lg == 0) {
      xf[0] = (_Float16)xA.x; xf[1] = (_Float16)xA.y;
      xf[2] = (_Float16)xA.z; xf[3] = (_Float16)xA.w;
      xf[4] = (_Float16)xB.x; xf[5] = (_Float16)xB.y;
      xf[6] = (_Float16)xB.z; xf[7] = (_Float16)xB.w;
    }
    {  // prefetch next x (consumed next step)
      const int tn = (t + 1 < TT) ? (t + 1) : (TT - 1);
      xA = xrow[2 * tn];
      xB = xrow[2 * tn + 1];
    }

    // ---- layer 0: gates0 = bias0 + Wih0@x + Whh0@h0[t-1] ----
    f32x4 acc[4];
#pragma unroll
    for (int ti = 0; ti < 4; ++ti) {
      acc[ti][0] = b0v[ti][0]; acc[ti][1] = b0v[ti][1];
      acc[ti][2] = b0v[ti][2]; acc[ti][3] = b0v[ti][3];
    }
#pragma unroll
    for (int ti = 0; ti < 4; ++ti)
      acc[ti] = __builtin_amdgcn_mfma_f32_16x16x32_f16(a_x[ti], xf, acc[ti], 0, 0, 0);
#pragma unroll
    for (int ti = 0; ti < 4; ++ti)
      acc[ti] = __builtin_amdgcn_mfma_f32_16x16x32_f16(a_h0[ti][0], hf0_0, acc[ti], 0, 0, 0);
#pragma unroll
    for (int ti = 0; ti < 4; ++ti)
      acc[ti] = __builtin_amdgcn_mfma_f32_16x16x32_f16(a_h0[ti][1], hf0_1, acc[ti], 0, 0, 0);

    // ---- act + c0/h0 update (wave-local) + publish h0[t] ----
#pragma unroll
    for (int r = 0; r < 4; ++r) {
      const float i_ = sigm(acc[0][r]);
      const float f_ = sigm(acc[1][r]);
      const float g_ = tanh_fast(acc[2][r]);
      const float o_ = sigm(acc[3][r]);
      c0v[r] = fmaf(f_, c0v[r], i_ * g_);
      const float h = o_ * tanh_fast(c0v[r]);
      const int k = 16 * q + 4 * lg + r;
      *(_Float16*)&h0buf[p][ar][16 * ((k >> 3) ^ (ar & 7)) + 2 * (k & 7)] = (_Float16)h;
    }
    __syncthreads();  // barrier 1: h0buf[p] ready; also fences h1buf[p] WAR

    // ---- read B-frags: h0[t] (for L1 + next step's L0), h1[t-1] ----
    hf0_0 = *(const f16x8*)&h0buf[p][ar][16 * ((0 + lg) ^ (ar & 7))];
    hf0_1 = *(const f16x8*)&h0buf[p][ar][16 * ((4 + lg) ^ (ar & 7))];
    hf1_0 = *(const f16x8*)&h1buf[p ^ 1][ar][16 * ((0 + lg) ^ (ar & 7))];
    hf1_1 = *(const f16x8*)&h1buf[p ^ 1][ar][16 * ((4 + lg) ^ (ar & 7))];

    // ---- layer 1: gates1 = bias1 + Wih1@h0[t] + Whh1@h1[t-1] ----
    f32x4 acd[4];
#pragma unroll
    for (int ti = 0; ti < 4; ++ti) {
      acd[ti][0] = b1v[ti][0]; acd[ti][1] = b1v[ti][1];
      acd[ti][2] = b1v[ti][2]; acd[ti][3] = b1v[ti][3];
    }
#pragma unroll
    for (int ti = 0; ti < 4; ++ti)
      acd[ti] = __builtin_amdgcn_mfma_f32_16x16x32_f16(a_i1[ti][0], hf0_0, acd[ti], 0, 0, 0);
#pragma unroll
    for (int ti = 0; ti < 4; ++ti)
      acd[ti] = __builtin_amdgcn_mfma_f32_16x16x32_f16(a_i1[ti][1], hf0_1, acd[ti], 0, 0, 0);
#pragma unroll
    for (int ti = 0; ti < 4; ++ti)
      acd[ti] = __builtin_amdgcn_mfma_f32_16x16x32_f16(a_h1[ti][0], hf1_0, acd[ti], 0, 0, 0);
#pragma unroll
    for (int ti = 0; ti < 4; ++ti)
      acd[ti] = __builtin_amdgcn_mfma_f32_16x16x32_f16(a_h1[ti][1], hf1_1, acd[ti], 0, 0, 0);

    // ---- act + c1/h1 update + publish h1[t] ----
#pragma unroll
    for (int r = 0; r < 4; ++r) {
      const float i_ = sigm(acd[0][r]);
      const float f_ = sigm(acd[1][r]);
      const float g_ = tanh_fast(acd[2][r]);
      const float o_ = sigm(acd[3][r]);
      c1v[r] = fmaf(f_, c1v[r], i_ * g_);
      const float h = o_ * tanh_fast(c1v[r]);
      hv1[r] = h;
      const int k = 16 * q + 4 * lg + r;
      *(_Float16*)&h1buf[p][ar][16 * ((k >> 3) ^ (ar & 7)) + 2 * (k & 7)] = (_Float16)h;
    }
    __syncthreads();  // barrier 2: h1buf[p] ready for step t+1
  }

  // ---- head: out[b] = h1[T-1] . w_out + b_out (exact fp32 h1 via LDS) ----
#pragma unroll
  for (int r = 0; r < 4; ++r) hout[16 * q + 4 * lg + r][ar] = hv1[r];
  __syncthreads();
  if (tid < NB) {
    float v = b_out[0];
    for (int k = 0; k < HH; ++k) v = fmaf(hout[k][tid], w_out[k], v);
    out[blockIdx.x * NB + tid] = v;
  }
}

extern "C" void kernel_launch(void* const* d_in, const int* in_sizes, int n_in,
                              void* d_out, int out_size, void* d_ws, size_t ws_size,
                              hipStream_t stream) {
  const float* x     = (const float*)d_in[0];
  const float* w_ih0 = (const float*)d_in[1];
  const float* w_hh0 = (const float*)d_in[2];
  const float* b_ih0 = (const float*)d_in[3];
  const float* b_hh0 = (const float*)d_in[4];
  const float* w_ih1 = (const float*)d_in[5];
  const float* w_hh1 = (const float*)d_in[6];
  const float* b_ih1 = (const float*)d_in[7];
  const float* b_hh1 = (const float*)d_in[8];
  const float* w_out = (const float*)d_in[9];
  const float* b_out = (const float*)d_in[10];
  float* out = (float*)d_out;

  lstm2_mfma<<<dim3(NBLK), dim3(256), 0, stream>>>(
      x, w_ih0, w_hh0, b_ih0, b_hh0,
      w_ih1, w_hh1, b_ih1, b_hh1,
      w_out, b_out, out);
}

// Round 8
// 2655.562 us; speedup vs baseline: 1.9161x; 1.2713x over previous
//
#include <hip/hip_runtime.h>

#define BB 512
#define TT 2048
#define DD 8
#define HH 64
#define NB 16              // batch columns per block (one MFMA N-tile)
#define NBLK (BB / NB)     // 32 blocks

typedef _Float16 f16x8 __attribute__((ext_vector_type(8)));
typedef __fp16   fp16x2 __attribute__((ext_vector_type(2)));  // cvt_pkrtz return type
typedef float    f32x4 __attribute__((ext_vector_type(4)));

// No fast-math in the harness: a literal 1.0f/x expands to the precise-div
// sequence (~10 instrs, 2 trans-rate). v_rcp_f32 is 1 instr, ~1ulp -- far
// below the fp16 weight-quantization error (5e-4) this kernel already
// carries. 40 divisions/thread-step made precise-div the dominant cost
// (R6: ~2400 of 3888 cyc/step unexplained by real work).
__device__ __forceinline__ float rcpf(float x) { return __builtin_amdgcn_rcpf(x); }
__device__ __forceinline__ float sigm(float x) {
  return rcpf(1.0f + __expf(-x));
}
__device__ __forceinline__ float tanh_fast(float x) {
  // tanh(x) = 1 - 2/(exp(2x)+1); saturates correctly at +/-inf
  return 1.0f - 2.0f * rcpf(__expf(2.0f * x) + 1.0f);
}
__device__ __forceinline__ f16x8 cvt8(const float* __restrict__ p) {
  f16x8 r;
#pragma unroll
  for (int e = 0; e < 8; ++e) r[e] = (_Float16)p[e];
  return r;
}
// pack 4 floats -> 4 fp16 in one uint2 via 2x v_cvt_pkrtz
__device__ __forceinline__ uint2 pk4(float a, float b, float c, float d) {
  union { fp16x2 h2[2]; uint2 u; } P;
  P.h2[0] = __builtin_amdgcn_cvt_pkrtz(a, b);
  P.h2[1] = __builtin_amdgcn_cvt_pkrtz(c, d);
  return P.u;
}

// MFMA 16x16x32 f16 layouts (gfx950):
//   A: row = lane&15, k = 8*(lane>>4)+e   (e = 0..7)
//   B: col = lane&15, k = 8*(lane>>4)+e
//   C/D: col = lane&15, row = 4*(lane>>4)+r  (r = 0..3)  [guide §3, m89-verified]
//
// Wave q owns M-tiles {q, q+4, q+8, q+12} = one tile of each gate type
// (i,f,g,o) covering hidden k in [16q, 16q+16). Hence the c/h update is
// wave-local in C-layout: lane holds i,f,g,o for 4 (k, n) pairs.
//
// h is republished per step as fp16 into LDS [n][64k], 16B-block XOR
// swizzle (blk ^= n&7). The 4 h values per lane are k-consecutive within
// one swizzle block -> packed via 2x v_cvt_pkrtz into ONE ds_write_b64
// (2-way banked = free). One conflict-free ds_read_b128 per B-fragment.
// Double-buffered by t-parity (WAR safety across the 2 barriers/step).
__global__ void __launch_bounds__(256, 1)
lstm2_mfma(const float* __restrict__ x,
           const float* __restrict__ w_ih0, const float* __restrict__ w_hh0,
           const float* __restrict__ b_ih0, const float* __restrict__ b_hh0,
           const float* __restrict__ w_ih1, const float* __restrict__ w_hh1,
           const float* __restrict__ b_ih1, const float* __restrict__ b_hh1,
           const float* __restrict__ w_out, const float* __restrict__ b_out,
           float* __restrict__ out)
{
  const int tid  = threadIdx.x;
  const int lane = tid & 63;
  const int q    = tid >> 6;    // wave 0..3
  const int lg   = lane >> 4;   // k-group 0..3
  const int ar   = lane & 15;   // A-row / B-col / batch n

  __shared__ __align__(16) unsigned char h0buf[2][NB][128];  // fp16 h0, parity-dbuf
  __shared__ __align__(16) unsigned char h1buf[2][NB][128];  // fp16 h1
  __shared__ float hout[HH][NB];

  // zero both parity buffers (h1buf[1] is read at t=0)
  {
    float* z0 = (float*)h0buf;
    float* z1 = (float*)h1buf;
    for (int i = tid; i < (int)(sizeof(h0buf) / 4); i += 256) { z0[i] = 0.f; z1[i] = 0.f; }
  }

  // ---- static A-fragments (fp16-packed, ~112 VGPRs) + biases ----
  f16x8 a_x[4], a_h0[4][2], a_i1[4][2], a_h1[4][2];
  float b0v[4][4], b1v[4][4];
#pragma unroll
  for (int ti = 0; ti < 4; ++ti) {
    const int tile = q + 4 * ti;        // ti: 0=i 1=f 2=g 3=o
    const int ga   = 16 * tile + ar;    // A-row gate index
    f16x8 zf = {};
    a_x[ti] = zf;
    if (lg == 0) a_x[ti] = cvt8(w_ih0 + ga * DD);   // k=0..7 live, rest 0
#pragma unroll
    for (int kf = 0; kf < 2; ++kf) {
      const int off = ga * HH + kf * 32 + lg * 8;
      a_h0[ti][kf] = cvt8(w_hh0 + off);
      a_i1[ti][kf] = cvt8(w_ih1 + off);
      a_h1[ti][kf] = cvt8(w_hh1 + off);
    }
#pragma unroll
    for (int r = 0; r < 4; ++r) {
      const int gc = 16 * tile + 4 * lg + r;        // C-row gate index
      b0v[ti][r] = b_ih0[gc] + b_hh0[gc];
      b1v[ti][r] = b_ih1[gc] + b_hh1[gc];
    }
  }

  // x stream: every lane tracks batch row `ar` (4-wave duplication -> L1 hits)
  const float4* xrow =
      (const float4*)(x + (size_t)(blockIdx.x * NB + ar) * TT * DD);
  float4 xA = xrow[0], xB = xrow[1];

  f16x8 hf0_0 = {}, hf0_1 = {}, hf1_0 = {}, hf1_1 = {};  // B-frags (h0[t-1], h1[t-1])
  float c0v[4] = {0.f, 0.f, 0.f, 0.f};
  float c1v[4] = {0.f, 0.f, 0.f, 0.f};
  float hv1[4] = {0.f, 0.f, 0.f, 0.f};

  // this lane's publish slot: k0 = 16q+4lg (4 consecutive fp16, 8B aligned)
  const int k0   = 16 * q + 4 * lg;
  const int pub  = 16 * ((k0 >> 3) ^ (ar & 7)) + 2 * (k0 & 7);

  __syncthreads();

  for (int t = 0; t < TT; ++t) {
    const int p = t & 1;

    // ---- build x B-frag (k=0..7 live in lane-group 0; A is 0 for k>=8) ----
    f16x8 xf = {};
    if (lg == 0) {
      xf[0] = (_Float16)xA.x; xf[1] = (_Float16)xA.y;
      xf[2] = (_Float16)xA.z; xf[3] = (_Float16)xA.w;
      xf[4] = (_Float16)xB.x; xf[5] = (_Float16)xB.y;
      xf[6] = (_Float16)xB.z; xf[7] = (_Float16)xB.w;
    }
    {  // prefetch next x (consumed next step)
      const int tn = (t + 1 < TT) ? (t + 1) : (TT - 1);
      xA = xrow[2 * tn];
      xB = xrow[2 * tn + 1];
    }

    // ---- layer 0: gates0 = bias0 + Wih0@x + Whh0@h0[t-1] ----
    f32x4 acc[4];
#pragma unroll
    for (int ti = 0; ti < 4; ++ti) {
      acc[ti][0] = b0v[ti][0]; acc[ti][1] = b0v[ti][1];
      acc[ti][2] = b0v[ti][2]; acc[ti][3] = b0v[ti][3];
    }
#pragma unroll
    for (int ti = 0; ti < 4; ++ti)
      acc[ti] = __builtin_amdgcn_mfma_f32_16x16x32_f16(a_x[ti], xf, acc[ti], 0, 0, 0);
#pragma unroll
    for (int ti = 0; ti < 4; ++ti)
      acc[ti] = __builtin_amdgcn_mfma_f32_16x16x32_f16(a_h0[ti][0], hf0_0, acc[ti], 0, 0, 0);
#pragma unroll
    for (int ti = 0; ti < 4; ++ti)
      acc[ti] = __builtin_amdgcn_mfma_f32_16x16x32_f16(a_h0[ti][1], hf0_1, acc[ti], 0, 0, 0);

    // ---- act + c0/h0 update (wave-local) + packed publish of h0[t] ----
    {
      float hv[4];
#pragma unroll
      for (int r = 0; r < 4; ++r) {
        const float i_ = sigm(acc[0][r]);
        const float f_ = sigm(acc[1][r]);
        const float g_ = tanh_fast(acc[2][r]);
        const float o_ = sigm(acc[3][r]);
        c0v[r] = fmaf(f_, c0v[r], i_ * g_);
        hv[r] = o_ * tanh_fast(c0v[r]);
      }
      *(uint2*)&h0buf[p][ar][pub] = pk4(hv[0], hv[1], hv[2], hv[3]);
    }
    __syncthreads();  // barrier 1: h0buf[p] ready; also fences h1buf[p] WAR

    // ---- read B-frags: h0[t] (for L1 + next step's L0), h1[t-1] ----
    hf0_0 = *(const f16x8*)&h0buf[p][ar][16 * ((0 + lg) ^ (ar & 7))];
    hf0_1 = *(const f16x8*)&h0buf[p][ar][16 * ((4 + lg) ^ (ar & 7))];
    hf1_0 = *(const f16x8*)&h1buf[p ^ 1][ar][16 * ((0 + lg) ^ (ar & 7))];
    hf1_1 = *(const f16x8*)&h1buf[p ^ 1][ar][16 * ((4 + lg) ^ (ar & 7))];

    // ---- layer 1: gates1 = bias1 + Wih1@h0[t] + Whh1@h1[t-1] ----
    f32x4 acd[4];
#pragma unroll
    for (int ti = 0; ti < 4; ++ti) {
      acd[ti][0] = b1v[ti][0]; acd[ti][1] = b1v[ti][1];
      acd[ti][2] = b1v[ti][2]; acd[ti][3] = b1v[ti][3];
    }
#pragma unroll
    for (int ti = 0; ti < 4; ++ti)
      acd[ti] = __builtin_amdgcn_mfma_f32_16x16x32_f16(a_i1[ti][0], hf0_0, acd[ti], 0, 0, 0);
#pragma unroll
    for (int ti = 0; ti < 4; ++ti)
      acd[ti] = __builtin_amdgcn_mfma_f32_16x16x32_f16(a_i1[ti][1], hf0_1, acd[ti], 0, 0, 0);
#pragma unroll
    for (int ti = 0; ti < 4; ++ti)
      acd[ti] = __builtin_amdgcn_mfma_f32_16x16x32_f16(a_h1[ti][0], hf1_0, acd[ti], 0, 0, 0);
#pragma unroll
    for (int ti = 0; ti < 4; ++ti)
      acd[ti] = __builtin_amdgcn_mfma_f32_16x16x32_f16(a_h1[ti][1], hf1_1, acd[ti], 0, 0, 0);

    // ---- act + c1/h1 update + packed publish of h1[t] ----
    {
#pragma unroll
      for (int r = 0; r < 4; ++r) {
        const float i_ = sigm(acd[0][r]);
        const float f_ = sigm(acd[1][r]);
        const float g_ = tanh_fast(acd[2][r]);
        const float o_ = sigm(acd[3][r]);
        c1v[r] = fmaf(f_, c1v[r], i_ * g_);
        hv1[r] = o_ * tanh_fast(c1v[r]);
      }
      *(uint2*)&h1buf[p][ar][pub] = pk4(hv1[0], hv1[1], hv1[2], hv1[3]);
    }
    __syncthreads();  // barrier 2: h1buf[p] ready for step t+1
  }

  // ---- head: out[b] = h1[T-1] . w_out + b_out (exact fp32 h1 via LDS) ----
#pragma unroll
  for (int r = 0; r < 4; ++r) hout[16 * q + 4 * lg + r][ar] = hv1[r];
  __syncthreads();
  if (tid < NB) {
    float v = b_out[0];
    for (int k = 0; k < HH; ++k) v = fmaf(hout[k][tid], w_out[k], v);
    out[blockIdx.x * NB + tid] = v;
  }
}

extern "C" void kernel_launch(void* const* d_in, const int* in_sizes, int n_in,
                              void* d_out, int out_size, void* d_ws, size_t ws_size,
                              hipStream_t stream) {
  const float* x     = (const float*)d_in[0];
  const float* w_ih0 = (const float*)d_in[1];
  const float* w_hh0 = (const float*)d_in[2];
  const float* b_ih0 = (const float*)d_in[3];
  const float* b_hh0 = (const float*)d_in[4];
  const float* w_ih1 = (const float*)d_in[5];
  const float* w_hh1 = (const float*)d_in[6];
  const float* b_ih1 = (const float*)d_in[7];
  const float* b_hh1 = (const float*)d_in[8];
  const float* w_out = (const float*)d_in[9];
  const float* b_out = (const float*)d_in[10];
  float* out = (float*)d_out;

  lstm2_mfma<<<dim3(NBLK), dim3(256), 0, stream>>>(
      x, w_ih0, w_hh0, b_ih0, b_hh0,
      w_ih1, w_hh1, b_ih1, b_hh1,
      w_out, b_out, out);
}

// Round 9
// 1823.764 us; speedup vs baseline: 2.7899x; 1.4561x over previous
//
#include <hip/hip_runtime.h>

#define BB 512
#define TT 2048
#define DD 8
#define HH 64
#define NB 16              // batch columns per block (one MFMA N-tile)
#define NBLK (BB / NB)     // 32 blocks

typedef _Float16 f16x8 __attribute__((ext_vector_type(8)));
typedef __fp16   fp16x2 __attribute__((ext_vector_type(2)));  // cvt_pkrtz return type
typedef float    f32x4 __attribute__((ext_vector_type(4)));

// v_rcp_f32 (1 instr) instead of precise-div (~10 instr): R8 confirmed
// -21% from this alone. ~1ulp, far below the fp16 weight error (5e-4).
__device__ __forceinline__ float rcpf(float x) { return __builtin_amdgcn_rcpf(x); }
__device__ __forceinline__ float sigm(float x) {
  return rcpf(1.0f + __expf(-x));
}
__device__ __forceinline__ float tanh_fast(float x) {
  // tanh(x) = 1 - 2/(exp(2x)+1); saturates correctly at +/-inf
  return 1.0f - 2.0f * rcpf(__expf(2.0f * x) + 1.0f);
}
__device__ __forceinline__ f16x8 cvt8(const float* __restrict__ p) {
  f16x8 r;
#pragma unroll
  for (int e = 0; e < 8; ++e) r[e] = (_Float16)p[e];
  return r;
}
// pack 4 floats -> 4 fp16 in one uint2 via 2x v_cvt_pkrtz
__device__ __forceinline__ uint2 pk4(float a, float b, float c, float d) {
  union { fp16x2 h2[2]; uint2 u; } P;
  P.h2[0] = __builtin_amdgcn_cvt_pkrtz(a, b);
  P.h2[1] = __builtin_amdgcn_cvt_pkrtz(c, d);
  return P.u;
}

// R9 structure: LAYER-PIPELINED single-barrier step.
// R8 measured step = ~3100 cyc with 2 barriers and strictly serial phases
// (MFMA-L0 -> act0 -> pub -> bar -> read -> MFMA-L1 -> act1 -> pub -> bar);
// per-wave issue floor is ~1600 cyc, rest is unhidden latency (1 wave/SIMD).
// L1[t] has a full step of slack, so iteration t now computes
//   h0[t]   = act0(bias0 + Wih0@x[t]   + Whh0@h0[t-1])
//   h1[t-1] = act1(bias1 + Wih1@h0[t-1] + Whh1@h1[t-2])
// from {h0[t-1], h1[t-2]} read after ONE barrier. The 12+16 MFMAs and the
// two act chains are independent -> each hides the other's latency.
// Biases live in persistent C-registers (MFMA D!=C: first MFMA of each
// chain reads them directly; kills 32 v_mov/step). x-frag built with
// v_cvt_pkrtz (4 instr). t==0 skips the L1 half (h1[-1]=0 stays in LDS).
__global__ void __launch_bounds__(256, 1)
lstm2_mfma(const float* __restrict__ x,
           const float* __restrict__ w_ih0, const float* __restrict__ w_hh0,
           const float* __restrict__ b_ih0, const float* __restrict__ b_hh0,
           const float* __restrict__ w_ih1, const float* __restrict__ w_hh1,
           const float* __restrict__ b_ih1, const float* __restrict__ b_hh1,
           const float* __restrict__ w_out, const float* __restrict__ b_out,
           float* __restrict__ out)
{
  const int tid  = threadIdx.x;
  const int lane = tid & 63;
  const int q    = tid >> 6;    // wave 0..3
  const int lg   = lane >> 4;   // k-group 0..3
  const int ar   = lane & 15;   // A-row / B-col / batch n

  __shared__ __align__(16) unsigned char h0buf[2][NB][128];  // fp16 h0, parity-dbuf
  __shared__ __align__(16) unsigned char h1buf[2][NB][128];  // fp16 h1
  __shared__ float hout[HH][NB];

  // zero both parity buffers (h0[-1], h1[-2], h1[-1] all read as 0)
  {
    float* z0 = (float*)h0buf;
    float* z1 = (float*)h1buf;
    for (int i = tid; i < (int)(sizeof(h0buf) / 4); i += 256) { z0[i] = 0.f; z1[i] = 0.f; }
  }

  // ---- static A-fragments (fp16-packed) + bias C-registers ----
  f16x8 a_x[4], a_h0[4][2], a_i1[4][2], a_h1[4][2];
  f32x4 bC0[4], bC1[4];   // persistent MFMA C operands (bias)
#pragma unroll
  for (int ti = 0; ti < 4; ++ti) {
    const int tile = q + 4 * ti;        // ti: 0=i 1=f 2=g 3=o
    const int ga   = 16 * tile + ar;    // A-row gate index
    f16x8 zf = {};
    a_x[ti] = zf;
    if (lg == 0) a_x[ti] = cvt8(w_ih0 + ga * DD);   // k=0..7 live, rest 0
#pragma unroll
    for (int kf = 0; kf < 2; ++kf) {
      const int off = ga * HH + kf * 32 + lg * 8;
      a_h0[ti][kf] = cvt8(w_hh0 + off);
      a_i1[ti][kf] = cvt8(w_ih1 + off);
      a_h1[ti][kf] = cvt8(w_hh1 + off);
    }
#pragma unroll
    for (int r = 0; r < 4; ++r) {
      const int gc = 16 * tile + 4 * lg + r;        // C-row gate index
      bC0[ti][r] = b_ih0[gc] + b_hh0[gc];
      bC1[ti][r] = b_ih1[gc] + b_hh1[gc];
    }
  }

  // x stream: every lane tracks batch row `ar` (4-wave duplication -> L1 hits)
  const float4* xrow =
      (const float4*)(x + (size_t)(blockIdx.x * NB + ar) * TT * DD);
  float4 xA = xrow[0], xB = xrow[1];

  float c0v[4] = {0.f, 0.f, 0.f, 0.f};
  float c1v[4] = {0.f, 0.f, 0.f, 0.f};
  float hv1[4] = {0.f, 0.f, 0.f, 0.f};

  // this lane's publish slot: k0 = 16q+4lg (4 consecutive fp16, 8B aligned)
  const int k0  = 16 * q + 4 * lg;
  const int pub = 16 * ((k0 >> 3) ^ (ar & 7)) + 2 * (k0 & 7);
  // B-frag read offsets (XOR swizzle, conflict-free ds_read_b128)
  const int rd0 = 16 * ((0 + lg) ^ (ar & 7));
  const int rd1 = 16 * ((4 + lg) ^ (ar & 7));

  __syncthreads();

  for (int t = 0; t <= TT; ++t) {
    const int p  = t & 1;      // publish parity
    const int rp = p ^ 1;      // read parity

    // ---- read h0[t-1], h1[t-2] B-frags ----
    const f16x8 hf0_0 = *(const f16x8*)&h0buf[rp][ar][rd0];
    const f16x8 hf0_1 = *(const f16x8*)&h0buf[rp][ar][rd1];
    const f16x8 hf1_0 = *(const f16x8*)&h1buf[rp][ar][rd0];
    const f16x8 hf1_1 = *(const f16x8*)&h1buf[rp][ar][rd1];

    // ---- x[t] B-frag via packed cvt (k=0..7 live in lane-group 0) ----
    f16x8 xf = {};
    if (lg == 0) {
      union { fp16x2 h2[4]; f16x8 v; } X;
      X.h2[0] = __builtin_amdgcn_cvt_pkrtz(xA.x, xA.y);
      X.h2[1] = __builtin_amdgcn_cvt_pkrtz(xA.z, xA.w);
      X.h2[2] = __builtin_amdgcn_cvt_pkrtz(xB.x, xB.y);
      X.h2[3] = __builtin_amdgcn_cvt_pkrtz(xB.z, xB.w);
      xf = X.v;
    }
    {  // prefetch next x (consumed next iteration; clamped at the tail)
      const int tn = (t + 1 < TT) ? (t + 1) : (TT - 1);
      xA = xrow[2 * tn];
      xB = xrow[2 * tn + 1];
    }

    // ---- L0 preacts: bias0 + Wih0@x[t] + Whh0@h0[t-1]  (12 MFMA) ----
    f32x4 acc[4];
#pragma unroll
    for (int ti = 0; ti < 4; ++ti)
      acc[ti] = __builtin_amdgcn_mfma_f32_16x16x32_f16(a_x[ti], xf, bC0[ti], 0, 0, 0);
#pragma unroll
    for (int ti = 0; ti < 4; ++ti)
      acc[ti] = __builtin_amdgcn_mfma_f32_16x16x32_f16(a_h0[ti][0], hf0_0, acc[ti], 0, 0, 0);
#pragma unroll
    for (int ti = 0; ti < 4; ++ti)
      acc[ti] = __builtin_amdgcn_mfma_f32_16x16x32_f16(a_h0[ti][1], hf0_1, acc[ti], 0, 0, 0);

    // ---- L1 preacts: bias1 + Wih1@h0[t-1] + Whh1@h1[t-2]  (16 MFMA) ----
    f32x4 acd[4];
#pragma unroll
    for (int ti = 0; ti < 4; ++ti)
      acd[ti] = __builtin_amdgcn_mfma_f32_16x16x32_f16(a_i1[ti][0], hf0_0, bC1[ti], 0, 0, 0);
#pragma unroll
    for (int ti = 0; ti < 4; ++ti)
      acd[ti] = __builtin_amdgcn_mfma_f32_16x16x32_f16(a_i1[ti][1], hf0_1, acd[ti], 0, 0, 0);
#pragma unroll
    for (int ti = 0; ti < 4; ++ti)
      acd[ti] = __builtin_amdgcn_mfma_f32_16x16x32_f16(a_h1[ti][0], hf1_0, acd[ti], 0, 0, 0);
#pragma unroll
    for (int ti = 0; ti < 4; ++ti)
      acd[ti] = __builtin_amdgcn_mfma_f32_16x16x32_f16(a_h1[ti][1], hf1_1, acd[ti], 0, 0, 0);

    // ---- act0 + c0/h0 update + publish h0[t] ----
    {
      float hv[4];
#pragma unroll
      for (int r = 0; r < 4; ++r) {
        const float i_ = sigm(acc[0][r]);
        const float f_ = sigm(acc[1][r]);
        const float g_ = tanh_fast(acc[2][r]);
        const float o_ = sigm(acc[3][r]);
        c0v[r] = fmaf(f_, c0v[r], i_ * g_);
        hv[r] = o_ * tanh_fast(c0v[r]);
      }
      *(uint2*)&h0buf[p][ar][pub] = pk4(hv[0], hv[1], hv[2], hv[3]);
    }

    // ---- act1 + c1/h1 update + publish h1[t-1] (skip at t==0: h1[-1]=0) ----
    if (t != 0) {
#pragma unroll
      for (int r = 0; r < 4; ++r) {
        const float i_ = sigm(acd[0][r]);
        const float f_ = sigm(acd[1][r]);
        const float g_ = tanh_fast(acd[2][r]);
        const float o_ = sigm(acd[3][r]);
        c1v[r] = fmaf(f_, c1v[r], i_ * g_);
        hv1[r] = o_ * tanh_fast(c1v[r]);
      }
      *(uint2*)&h1buf[p][ar][pub] = pk4(hv1[0], hv1[1], hv1[2], hv1[3]);
    }

    __syncthreads();  // the ONE barrier: h0[t], h1[t-1] visible for iter t+1
  }

  // ---- head: out[b] = h1[T-1] . w_out + b_out (exact fp32 h1 via LDS) ----
#pragma unroll
  for (int r = 0; r < 4; ++r) hout[16 * q + 4 * lg + r][ar] = hv1[r];
  __syncthreads();
  if (tid < NB) {
    float v = b_out[0];
    for (int k = 0; k < HH; ++k) v = fmaf(hout[k][tid], w_out[k], v);
    out[blockIdx.x * NB + tid] = v;
  }
}

extern "C" void kernel_launch(void* const* d_in, const int* in_sizes, int n_in,
                              void* d_out, int out_size, void* d_ws, size_t ws_size,
                              hipStream_t stream) {
  const float* x     = (const float*)d_in[0];
  const float* w_ih0 = (const float*)d_in[1];
  const float* w_hh0 = (const float*)d_in[2];
  const float* b_ih0 = (const float*)d_in[3];
  const float* b_hh0 = (const float*)d_in[4];
  const float* w_ih1 = (const float*)d_in[5];
  const float* w_hh1 = (const float*)d_in[6];
  const float* b_ih1 = (const float*)d_in[7];
  const float* b_hh1 = (const float*)d_in[8];
  const float* w_out = (const float*)d_in[9];
  const float* b_out = (const float*)d_in[10];
  float* out = (float*)d_out;

  lstm2_mfma<<<dim3(NBLK), dim3(256), 0, stream>>>(
      x, w_ih0, w_hh0, b_ih0, b_hh0,
      w_ih1, w_hh1, b_ih1, b_hh1,
      w_out, b_out, out);
}

// Round 11
// 1692.610 us; speedup vs baseline: 3.0061x; 1.0775x over previous
//
#include <hip/hip_runtime.h>

#define BB 512
#define TT 2048
#define DD 8
#define HH 64
#define NB 16              // batch columns per block (one MFMA N-tile)
#define NBLK (BB / NB)     // 32 blocks

typedef _Float16 f16x8 __attribute__((ext_vector_type(8)));
typedef __fp16   fp16x2 __attribute__((ext_vector_type(2)));  // cvt_pkrtz return type
typedef float    f32x4 __attribute__((ext_vector_type(4)));

// v_rcp_f32 (1 instr) instead of precise-div (~10 instr): R8 confirmed
// -21% from this alone. ~1ulp, far below the fp16 weight error (5e-4).
__device__ __forceinline__ float rcpf(float x) { return __builtin_amdgcn_rcpf(x); }
__device__ __forceinline__ float sigm(float x) {
  return rcpf(1.0f + __expf(-x));
}
__device__ __forceinline__ float tanh_fast(float x) {
  // tanh(x) = 1 - 2/(exp(2x)+1); saturates correctly at +/-inf
  return 1.0f - 2.0f * rcpf(__expf(2.0f * x) + 1.0f);
}
__device__ __forceinline__ f16x8 cvt8(const float* __restrict__ p) {
  f16x8 r;
#pragma unroll
  for (int e = 0; e < 8; ++e) r[e] = (_Float16)p[e];
  return r;
}
// pack 4 floats -> 4 fp16 in one uint2 via 2x v_cvt_pkrtz
__device__ __forceinline__ uint2 pk4(float a, float b, float c, float d) {
  union { fp16x2 h2[2]; uint2 u; } P;
  P.h2[0] = __builtin_amdgcn_cvt_pkrtz(a, b);
  P.h2[1] = __builtin_amdgcn_cvt_pkrtz(c, d);
  return P.u;
}

// R11 = R10 resubmit (R10 died to container infra, not kernel content:
// all barriers are convergence-safe, no OOB, LDS 12.3KB).
// Structure: LAYER-SPLIT WAVES on the R9 single-barrier pipelined step.
// R9 measured ~2060 cyc/step vs ~910-cyc per-SIMD issue floor (640 = 80
// transcendentals x 8 cyc); the gap is dependency latency at 1 wave/SIMD.
// 512 threads: waves 0-3 = layer 0, waves 4-7 = layer 1. Each SIMD hosts
// one L0-wave + one L1-wave -> two independent streams hide each other's
// trans/MFMA latency. Same single barrier, now syncing 8 waves.
//   iter t:  L0-waves: h0[t]   = act0(bias0 + Wih0@x[t]    + Whh0@h0[t-1])
//            L1-waves: h1[t-1] = act1(bias1 + Wih1@h0[t-1] + Whh1@h1[t-2])
__global__ void __launch_bounds__(512, 1)
lstm2_mfma(const float* __restrict__ x,
           const float* __restrict__ w_ih0, const float* __restrict__ w_hh0,
           const float* __restrict__ b_ih0, const float* __restrict__ b_hh0,
           const float* __restrict__ w_ih1, const float* __restrict__ w_hh1,
           const float* __restrict__ b_ih1, const float* __restrict__ b_hh1,
           const float* __restrict__ w_out, const float* __restrict__ b_out,
           float* __restrict__ out)
{
  const int tid  = threadIdx.x;
  const int lane = tid & 63;
  const int wq   = tid >> 6;    // wave 0..7
  const int lay  = wq >> 2;     // 0: layer-0 wave, 1: layer-1 wave
  const int q    = wq & 3;      // k-slice index 0..3 within the layer
  const int lg   = lane >> 4;   // k-group 0..3
  const int ar   = lane & 15;   // A-row / B-col / batch n

  __shared__ __align__(16) unsigned char h0buf[2][NB][128];  // fp16 h0, parity-dbuf
  __shared__ __align__(16) unsigned char h1buf[2][NB][128];  // fp16 h1
  __shared__ float hout[HH][NB];

  // zero both parity buffers (h0[-1], h1[-2], h1[-1] all read as 0)
  {
    float* z0 = (float*)h0buf;
    float* z1 = (float*)h1buf;
    for (int i = tid; i < (int)(sizeof(h0buf) / 4); i += 512) { z0[i] = 0.f; z1[i] = 0.f; }
  }

  // ---- static A-fragments (this wave's layer only) + bias C-registers ----
  // L0 waves: a_x = w_ih0 (k<8), aU = w_hh0.   L1 waves: aU = w_ih1, aV = w_hh1.
  f16x8 a_x[4];
  f16x8 aU[4][2];
  f16x8 aV[4][2];
  f32x4 bC[4];         // bias as persistent MFMA C operand
#pragma unroll
  for (int ti = 0; ti < 4; ++ti) {
    const int tile = q + 4 * ti;        // ti: 0=i 1=f 2=g 3=o
    const int ga   = 16 * tile + ar;    // A-row gate index
    f16x8 zf = {};
    a_x[ti] = zf;
    if (lay == 0) {
      if (lg == 0) a_x[ti] = cvt8(w_ih0 + ga * DD);   // k=0..7 live, rest 0
#pragma unroll
      for (int kf = 0; kf < 2; ++kf) {
        const int off = ga * HH + kf * 32 + lg * 8;
        aU[ti][kf] = cvt8(w_hh0 + off);
        aV[ti][kf] = zf;  // unused on L0 waves
      }
#pragma unroll
      for (int r = 0; r < 4; ++r) {
        const int gc = 16 * tile + 4 * lg + r;
        bC[ti][r] = b_ih0[gc] + b_hh0[gc];
      }
    } else {
#pragma unroll
      for (int kf = 0; kf < 2; ++kf) {
        const int off = ga * HH + kf * 32 + lg * 8;
        aU[ti][kf] = cvt8(w_ih1 + off);
        aV[ti][kf] = cvt8(w_hh1 + off);
      }
#pragma unroll
      for (int r = 0; r < 4; ++r) {
        const int gc = 16 * tile + 4 * lg + r;
        bC[ti][r] = b_ih1[gc] + b_hh1[gc];
      }
    }
  }

  // x stream (L0 waves only): lane tracks batch row `ar`
  const float4* xrow =
      (const float4*)(x + (size_t)(blockIdx.x * NB + ar) * TT * DD);
  float4 xA = make_float4(0, 0, 0, 0), xB = make_float4(0, 0, 0, 0);
  if (lay == 0) { xA = xrow[0]; xB = xrow[1]; }

  float cv[4]  = {0.f, 0.f, 0.f, 0.f};   // c-state of this wave's layer
  float hv1[4] = {0.f, 0.f, 0.f, 0.f};   // L1 waves: h1[t-1] (for head)

  // this lane's publish slot: k0 = 16q+4lg (4 consecutive fp16, 8B aligned)
  const int k0  = 16 * q + 4 * lg;
  const int pub = 16 * ((k0 >> 3) ^ (ar & 7)) + 2 * (k0 & 7);
  // B-frag read offsets (XOR swizzle, conflict-free ds_read_b128)
  const int rd0 = 16 * ((0 + lg) ^ (ar & 7));
  const int rd1 = 16 * ((4 + lg) ^ (ar & 7));

  __syncthreads();

  for (int t = 0; t <= TT; ++t) {
    const int p  = t & 1;      // publish parity
    const int rp = p ^ 1;      // read parity

    if (lay == 0) {
      // ---- L0: h0[t] = act0(bias0 + Wih0@x[t] + Whh0@h0[t-1]) ----
      const f16x8 hf0_0 = *(const f16x8*)&h0buf[rp][ar][rd0];
      const f16x8 hf0_1 = *(const f16x8*)&h0buf[rp][ar][rd1];

      f16x8 xf = {};
      if (lg == 0) {
        union { fp16x2 h2[4]; f16x8 v; } X;
        X.h2[0] = __builtin_amdgcn_cvt_pkrtz(xA.x, xA.y);
        X.h2[1] = __builtin_amdgcn_cvt_pkrtz(xA.z, xA.w);
        X.h2[2] = __builtin_amdgcn_cvt_pkrtz(xB.x, xB.y);
        X.h2[3] = __builtin_amdgcn_cvt_pkrtz(xB.z, xB.w);
        xf = X.v;
      }
      {  // prefetch next x (consumed next iteration; clamped at tail)
        const int tn = (t + 1 < TT) ? (t + 1) : (TT - 1);
        xA = xrow[2 * tn];
        xB = xrow[2 * tn + 1];
      }

      f32x4 acc[4];
#pragma unroll
      for (int ti = 0; ti < 4; ++ti)
        acc[ti] = __builtin_amdgcn_mfma_f32_16x16x32_f16(a_x[ti], xf, bC[ti], 0, 0, 0);
#pragma unroll
      for (int ti = 0; ti < 4; ++ti)
        acc[ti] = __builtin_amdgcn_mfma_f32_16x16x32_f16(aU[ti][0], hf0_0, acc[ti], 0, 0, 0);
#pragma unroll
      for (int ti = 0; ti < 4; ++ti)
        acc[ti] = __builtin_amdgcn_mfma_f32_16x16x32_f16(aU[ti][1], hf0_1, acc[ti], 0, 0, 0);

      float hv[4];
#pragma unroll
      for (int r = 0; r < 4; ++r) {
        const float i_ = sigm(acc[0][r]);
        const float f_ = sigm(acc[1][r]);
        const float g_ = tanh_fast(acc[2][r]);
        const float o_ = sigm(acc[3][r]);
        cv[r] = fmaf(f_, cv[r], i_ * g_);
        hv[r] = o_ * tanh_fast(cv[r]);
      }
      *(uint2*)&h0buf[p][ar][pub] = pk4(hv[0], hv[1], hv[2], hv[3]);
    } else {
      // ---- L1: h1[t-1] = act1(bias1 + Wih1@h0[t-1] + Whh1@h1[t-2]) ----
      const f16x8 hf0_0 = *(const f16x8*)&h0buf[rp][ar][rd0];
      const f16x8 hf0_1 = *(const f16x8*)&h0buf[rp][ar][rd1];
      const f16x8 hf1_0 = *(const f16x8*)&h1buf[rp][ar][rd0];
      const f16x8 hf1_1 = *(const f16x8*)&h1buf[rp][ar][rd1];

      f32x4 acd[4];
#pragma unroll
      for (int ti = 0; ti < 4; ++ti)
        acd[ti] = __builtin_amdgcn_mfma_f32_16x16x32_f16(aU[ti][0], hf0_0, bC[ti], 0, 0, 0);
#pragma unroll
      for (int ti = 0; ti < 4; ++ti)
        acd[ti] = __builtin_amdgcn_mfma_f32_16x16x32_f16(aU[ti][1], hf0_1, acd[ti], 0, 0, 0);
#pragma unroll
      for (int ti = 0; ti < 4; ++ti)
        acd[ti] = __builtin_amdgcn_mfma_f32_16x16x32_f16(aV[ti][0], hf1_0, acd[ti], 0, 0, 0);
#pragma unroll
      for (int ti = 0; ti < 4; ++ti)
        acd[ti] = __builtin_amdgcn_mfma_f32_16x16x32_f16(aV[ti][1], hf1_1, acd[ti], 0, 0, 0);

      if (t != 0) {
#pragma unroll
        for (int r = 0; r < 4; ++r) {
          const float i_ = sigm(acd[0][r]);
          const float f_ = sigm(acd[1][r]);
          const float g_ = tanh_fast(acd[2][r]);
          const float o_ = sigm(acd[3][r]);
          cv[r] = fmaf(f_, cv[r], i_ * g_);
          hv1[r] = o_ * tanh_fast(cv[r]);
        }
        *(uint2*)&h1buf[p][ar][pub] = pk4(hv1[0], hv1[1], hv1[2], hv1[3]);
      }
    }

    __syncthreads();  // h0[t], h1[t-1] visible for iter t+1
  }

  // ---- head: out[b] = h1[T-1] . w_out + b_out (L1 waves hold exact h1) ----
  if (lay == 1) {
#pragma unroll
    for (int r = 0; r < 4; ++r) hout[16 * q + 4 * lg + r][ar] = hv1[r];
  }
  __syncthreads();
  if (tid < NB) {
    float v = b_out[0];
    for (int k = 0; k < HH; ++k) v = fmaf(hout[k][tid], w_out[k], v);
    out[blockIdx.x * NB + tid] = v;
  }
}

extern "C" void kernel_launch(void* const* d_in, const int* in_sizes, int n_in,
                              void* d_out, int out_size, void* d_ws, size_t ws_size,
                              hipStream_t stream) {
  const float* x     = (const float*)d_in[0];
  const float* w_ih0 = (const float*)d_in[1];
  const float* w_hh0 = (const float*)d_in[2];
  const float* b_ih0 = (const float*)d_in[3];
  const float* b_hh0 = (const float*)d_in[4];
  const float* w_ih1 = (const float*)d_in[5];
  const float* w_hh1 = (const float*)d_in[6];
  const float* b_ih1 = (const float*)d_in[7];
  const float* b_hh1 = (const float*)d_in[8];
  const float* w_out = (const float*)d_in[9];
  const float* b_out = (const float*)d_in[10];
  float* out = (float*)d_out;

  lstm2_mfma<<<dim3(NBLK), dim3(512), 0, stream>>>(
      x, w_ih0, w_hh0, b_ih0, b_hh0,
      w_ih1, w_hh1, b_ih1, b_hh1,
      w_out, b_out, out);
}